// Round 12
// baseline (186.117 us; speedup 1.0000x reference)
//
#include <hip/hip_runtime.h>
#include <hip/hip_bf16.h>
#include <math.h>

#define H_ 1024
#define NH_ 16
#define HD_ 64
#define B_ 2
#define SQ_ 2048
#define SK_ 2048

using bf16x8 = __attribute__((ext_vector_type(8))) short;
using f32x4  = __attribute__((ext_vector_type(4))) float;
using f32x16 = __attribute__((ext_vector_type(16))) float;

static __device__ __forceinline__ unsigned short f2bf(float f) {
  union { float f; unsigned u; } v; v.f = f;
  unsigned r = v.u + 0x7fffu + ((v.u >> 16) & 1u);
  return (unsigned short)(r >> 16);
}

// two f32 -> packed bf16x2 dword via HW cvt (lo = a, hi = b)
static __device__ __forceinline__ unsigned cvtpk(float a, float b) {
  unsigned r;
  asm("v_cvt_pk_bf16_f32 %0, %1, %2" : "=v"(r) : "v"(a), "v"(b));
  return r;
}

static __device__ __forceinline__ void gl2lds16(const void* g, void* l) {
  __builtin_amdgcn_global_load_lds(
      (const __attribute__((address_space(1))) unsigned int*)g,
      (__attribute__((address_space(3))) unsigned int*)l, 16, 0, 0);
}

// swizzled index (shorts) within a [rows][64-short] tile, 128B rows
static __device__ __forceinline__ int sidx(int row, int cbyte) {
  return row * 64 + (((cbyte) ^ ((row & 7) << 4)) >> 1);
}

// ------------- merged activation convert: attender->cat, attendee->aet ------
__global__ __launch_bounds__(256) void conv_act(
    const float* __restrict__ att, const float* __restrict__ ate,
    unsigned short* __restrict__ cat, unsigned short* __restrict__ aet) {
  const long NV = (long)4096 * 1024 / 8;  // vec8 chunks per tensor
  for (long i = blockIdx.x * 256L + threadIdx.x; i < 2 * NV;
       i += (long)gridDim.x * 256) {
    const float* s;
    unsigned short* d;
    if (i < NV) {
      long e = i * 8;
      int r = (int)(e >> 10), c = (int)(e & 1023);
      s = att + e;
      d = cat + (long)r * 2048 + c;
    } else {
      long e = (i - NV) * 8;
      s = ate + e;
      d = aet + e;
    }
    unsigned short tmp[8];
#pragma unroll
    for (int j = 0; j < 8; ++j) tmp[j] = f2bf(s[j]);
    *(uint4*)d = *(uint4*)tmp;
  }
}

// ------------- merged weight transpose-convert (3 segments) -----------------
// f32 (R,C) -> bf16 (C,R). grid 1536: [0,768) attn_w, [768,1024) proj, rest mlp
__global__ __launch_bounds__(256) void convT3(
    const float* __restrict__ w_at, const float* __restrict__ w_pr,
    const float* __restrict__ w_ml, unsigned short* __restrict__ o_at,
    unsigned short* __restrict__ o_pr, unsigned short* __restrict__ o_ml) {
  __shared__ __align__(16) unsigned short Ls[64][68];
  int bx = blockIdx.x;
  const float* in;
  unsigned short* out;
  int R, C;
  if (bx < 768) {
    in = w_at; out = o_at; R = 1024; C = 3072;
  } else if (bx < 1024) {
    in = w_pr; out = o_pr; R = 1024; C = 1024; bx -= 768;
  } else {
    in = w_ml; out = o_ml; R = 2048; C = 1024; bx -= 1024;
  }
  int nct = C >> 6;
  int tr = bx / nct, tc = bx % nct;
  int r0 = tr * 64, c0 = tc * 64;
  int rr = threadIdx.x >> 4;
  int cc = (threadIdx.x & 15) * 4;
#pragma unroll
  for (int i = 0; i < 4; ++i) {
    int r = rr + 16 * i;
    float4 v = *(const float4*)&in[(long)(r0 + r) * C + c0 + cc];
    unsigned short t[4] = {f2bf(v.x), f2bf(v.y), f2bf(v.z), f2bf(v.w)};
    *(unsigned long long*)&Ls[r][cc] = *(unsigned long long*)t;
  }
  __syncthreads();
  int oc = threadIdx.x >> 2;
  int orr = (threadIdx.x & 3) * 16;
  unsigned short t[16];
#pragma unroll
  for (int j = 0; j < 16; ++j) t[j] = Ls[orr + j][oc];
  *(uint4*)&out[(long)(c0 + oc) * R + r0 + orr] = *(uint4*)&t[0];
  *(uint4*)&out[(long)(c0 + oc) * R + r0 + orr + 8] = *(uint4*)&t[8];
}

// ---------------- bf16 GEMM, B^T input, BK=64, double-buffered, swizzled ----
// Out = A(MxK) @ W(KxN) + bias, Bw = W^T (N rows, K cols). BN = NF*32.
// MODE 0: bf16 out0 (scaled by oscale). MODE 1: f32 out0 + GELU.
// MODE 2: split KV (col<H -> bf16 K*mask to out0; col>=H -> V^T to out1).
template <int NF, int MODE>
__global__ __launch_bounds__(256) void gemm_bt(
    const unsigned short* __restrict__ A, int lda,
    const unsigned short* __restrict__ Bw, int ldb,
    const float* __restrict__ bias, const int* __restrict__ msk, float oscale,
    void* __restrict__ out0, void* __restrict__ out1, int ldo, int K) {
  __shared__ __align__(16) unsigned short Al[2][128 * 64];
  __shared__ __align__(16) unsigned short Bl[2][NF * 32 * 64];
  const int tid = threadIdx.x;
  const int l = tid & 63, w = tid >> 6;
  const int wr = w >> 1, wc = w & 1;
  const int lq = l & 15, lh = l >> 4;
  const int m0 = blockIdx.y * 128, n0 = blockIdx.x * (NF * 32);

  const int swcol = (((tid & 7) ^ ((tid >> 3) & 7)) << 3);  // shorts
  const int rbase = w * 8 + (l >> 3);
  const unsigned short* gA = A + (long)(m0 + rbase) * lda + swcol;
  const unsigned short* gB = Bw + (long)(n0 + rbase) * ldb + swcol;

  f32x4 acc[4][NF];
#pragma unroll
  for (int a = 0; a < 4; ++a)
#pragma unroll
    for (int b = 0; b < NF; ++b) acc[a][b] = (f32x4){0.f, 0.f, 0.f, 0.f};

  auto stage = [&](int k0, int buf) {
#pragma unroll
    for (int i = 0; i < 4; ++i)
      gl2lds16(gA + (long)(i * 32) * lda + k0, &Al[buf][i * 2048 + w * 512]);
#pragma unroll
    for (int i = 0; i < NF; ++i)
      gl2lds16(gB + (long)(i * 32) * ldb + k0, &Bl[buf][i * 2048 + w * 512]);
  };

  const int NT = K >> 6;
  stage(0, 0);
  __syncthreads();
  int cur = 0;
  for (int t = 0; t < NT; ++t) {
    if (t + 1 < NT) stage((t + 1) << 6, cur ^ 1);
    bf16x8 af[4][2], bfr[NF][2];
#pragma unroll
    for (int a = 0; a < 4; ++a) {
      int row = wr * 64 + a * 16 + lq;
#pragma unroll
      for (int kk = 0; kk < 2; ++kk)
        af[a][kk] = *(const bf16x8*)&Al[cur][sidx(row, kk * 64 + lh * 16)];
    }
#pragma unroll
    for (int b = 0; b < NF; ++b) {
      int row = wc * (NF * 16) + b * 16 + lq;
#pragma unroll
      for (int kk = 0; kk < 2; ++kk)
        bfr[b][kk] = *(const bf16x8*)&Bl[cur][sidx(row, kk * 64 + lh * 16)];
    }
#pragma unroll
    for (int kk = 0; kk < 2; ++kk)
#pragma unroll
      for (int a = 0; a < 4; ++a)
#pragma unroll
        for (int b = 0; b < NF; ++b)
          acc[a][b] = __builtin_amdgcn_mfma_f32_16x16x32_bf16(
              af[a][kk], bfr[b][kk], acc[a][b], 0, 0, 0);
    __syncthreads();
    cur ^= 1;
  }

#pragma unroll
  for (int a = 0; a < 4; ++a) {
#pragma unroll
    for (int bb = 0; bb < NF; ++bb) {
      int col = n0 + wc * (NF * 16) + bb * 16 + lq;
      float bv = bias[col];
      int row0 = m0 + wr * 64 + a * 16 + lh * 4;
      if (MODE == 0) {
        unsigned short* O = (unsigned short*)out0;
#pragma unroll
        for (int r = 0; r < 4; ++r)
          O[(long)(row0 + r) * ldo + col] = f2bf((acc[a][bb][r] + bv) * oscale);
      } else if (MODE == 1) {
        float* O = (float*)out0;
#pragma unroll
        for (int r = 0; r < 4; ++r) {
          float v = acc[a][bb][r] + bv;
          float y = 0.7978845608028654f * (v + 0.044715f * v * v * v);
          O[(long)(row0 + r) * ldo + col] =
              v * __builtin_amdgcn_rcpf(1.f + __expf(-2.f * y));
        }
      } else {
        if (col < H_) {
          unsigned short* O = (unsigned short*)out0;
#pragma unroll
          for (int r = 0; r < 4; ++r) {
            float mk = (float)msk[row0 + r];
            O[(long)(row0 + r) * ldo + col] = f2bf((acc[a][bb][r] + bv) * mk);
          }
        } else {
          int vcol = col - H_, hh = vcol >> 6, dd = vcol & 63;
          int bi = row0 >> 11, k = row0 & 2047;
          unsigned short t[4];
#pragma unroll
          for (int r = 0; r < 4; ++r) t[r] = f2bf(acc[a][bb][r] + bv);
          *(unsigned long long*)((unsigned short*)out1 +
                                 (((long)(bi * NH_ + hh) * HD_ + dd) << 11) + k) =
              *(unsigned long long*)t;
        }
      }
    }
  }
}

// ---------------- flash attention: 32x32 MFMA, in-reg P, split-K x2 ---------
// grid 1024 (XCD-remapped; both splits of a (b,h) on one XCD), 4 waves x 32 q.
// Each block covers 16 of 32 KV tiles; writes f32 partial O and partial l.
// Q pre-scaled by log2(e); K pre-masked; V pre-transposed (B,NH,HD,SK).
__global__ __launch_bounds__(256) void flash_attn(
    const unsigned short* __restrict__ Qb,
    const unsigned short* __restrict__ Kb,
    const unsigned short* __restrict__ Vtg,
    float* __restrict__ Op, float* __restrict__ Lp) {
  __shared__ __align__(16) unsigned short Kl[2][64 * 64];
  __shared__ __align__(16) unsigned short Vl[2][64 * 64];
  const int tid = threadIdx.x;
  const int l = tid & 63, w = tid >> 6;
  const int lo = l & 31, hi = l >> 5;
  const int id = blockIdx.x;
  const int xcd = id & 7, sub = id >> 3;      // sub: 0..127
  const int pair = xcd * 4 + (sub >> 5);      // (b*NH+h): 4 pairs per XCD
  const int rem = sub & 31;
  const int qb = rem & 15, sp = rem >> 4;     // q-tile, K-split
  const int b = pair >> 4, h = pair & 15;
  const int brow = b * SQ_ + qb * 128 + w * 32;

  // Q B-fragments (32x32x16: lane holds Q[q=lo][d = dstep*16 + hi*8 + j])
  bf16x8 qf[4];
  {
    const unsigned short* qp = Qb + (long)(brow + lo) * H_ + h * HD_ + hi * 8;
#pragma unroll
    for (int d = 0; d < 4; ++d) qf[d] = *(const bf16x8*)(qp + d * 16);
  }

  // staging: lane covers rows j*32 + w*8 + (l>>3), bytecol (l&7)*16 (j=0,1);
  // source col pre-swizzled so linear LDS dest lands XOR-swizzled (rule #21)
  const int srow = w * 8 + (l >> 3);
  const int swc = ((l & 7) ^ ((l >> 3) & 7)) << 3;  // shorts
  const unsigned short* Kg = Kb + ((long)b * SK_ + srow) * H_ + h * HD_ + swc;
  const unsigned short* Vg = Vtg + ((long)(b * NH_ + h) * HD_ + srow) * SK_ + swc;

  auto stage = [&](int kt, int buf) {
    const unsigned short* ks = Kg + (long)kt * 64 * H_;
    const unsigned short* vs = Vg + kt * 64;
    char* kd = (char*)&Kl[buf][0] + w * 1024;
    char* vd = (char*)&Vl[buf][0] + w * 1024;
    gl2lds16(ks, kd);
    gl2lds16(ks + (long)32 * H_, kd + 4096);
    gl2lds16(vs, vd);
    gl2lds16(vs + (long)32 * SK_, vd + 4096);
  };

  f32x16 zreg, accO[2];
#pragma unroll
  for (int r = 0; r < 16; ++r) zreg[r] = 0.f;
#pragma unroll
  for (int i = 0; i < 2; ++i)
#pragma unroll
    for (int r = 0; r < 16; ++r) accO[i][r] = 0.f;
  float l_run = 0.f;

  const int kt0 = sp * 16, kt1 = kt0 + 16;
  stage(kt0, 0);
  __syncthreads();
  int cur = 0;
  for (int kt = kt0; kt < kt1; ++kt) {
    if (kt + 1 < kt1) stage(kt + 1, cur ^ 1);
    const unsigned short* Kc = &Kl[cur][0];
    const unsigned short* Vc = &Vl[cur][0];

    // S^T[k][q] = K_tile(64x64) @ Q^T(64x32): two 32x32 halves over k.
    // ds=0 peeled with C = persistent zero reg (no per-tile acc zero-init).
    __builtin_amdgcn_s_setprio(1);
    bf16x8 ka0 = *(const bf16x8*)&Kc[sidx(lo, hi * 16)];
    bf16x8 ka1 = *(const bf16x8*)&Kc[sidx(32 + lo, hi * 16)];
    f32x16 s0 = __builtin_amdgcn_mfma_f32_32x32x16_bf16(ka0, qf[0], zreg, 0, 0, 0);
    f32x16 s1 = __builtin_amdgcn_mfma_f32_32x32x16_bf16(ka1, qf[0], zreg, 0, 0, 0);
#pragma unroll
    for (int ds = 1; ds < 4; ++ds) {
      ka0 = *(const bf16x8*)&Kc[sidx(lo, ds * 32 + hi * 16)];
      ka1 = *(const bf16x8*)&Kc[sidx(32 + lo, ds * 32 + hi * 16)];
      s0 = __builtin_amdgcn_mfma_f32_32x32x16_bf16(ka0, qf[ds], s0, 0, 0, 0);
      s1 = __builtin_amdgcn_mfma_f32_32x32x16_bf16(ka1, qf[ds], s1, 0, 0, 0);
    }
    __builtin_amdgcn_s_setprio(0);

    // P = 2^s (Q carries log2e; shift-free, cancels in normalization).
    // Lane holds, for q=lo, k = kh*32 + 4*hi + {(r&3)+8*(r>>2)}.
    // Assemble PV A-frags (k = kstep*16 + hi*8 + j) via cvt_pk + permlane32.
    bf16x8 pa[4];
    float ps = 0.f;
#pragma unroll
    for (int kh = 0; kh < 2; ++kh) {
      const f32x16& s = kh ? s1 : s0;
      float p[16];
#pragma unroll
      for (int r = 0; r < 16; ++r) { p[r] = exp2f(s[r]); ps += p[r]; }
#pragma unroll
      for (int g = 0; g < 2; ++g) {
        unsigned X0 = cvtpk(p[g * 8 + 0], p[g * 8 + 1]);
        unsigned X1 = cvtpk(p[g * 8 + 2], p[g * 8 + 3]);
        unsigned Y0 = cvtpk(p[g * 8 + 4], p[g * 8 + 5]);
        unsigned Y1 = cvtpk(p[g * 8 + 6], p[g * 8 + 7]);
        asm("v_permlane32_swap_b32 %0, %1" : "+v"(X0), "+v"(Y0));
        asm("v_permlane32_swap_b32 %0, %1" : "+v"(X1), "+v"(Y1));
        union { unsigned u[4]; bf16x8 v; } cc;
        cc.u[0] = X0; cc.u[1] = X1; cc.u[2] = Y0; cc.u[3] = Y1;
        pa[kh * 2 + g] = cc.v;
      }
    }
    l_run += ps;

    // O[q][d] += P(32x64) @ V(64x64): two 32x32 outputs over d
    __builtin_amdgcn_s_setprio(1);
#pragma unroll
    for (int dh = 0; dh < 2; ++dh)
#pragma unroll
      for (int ks = 0; ks < 4; ++ks) {
        bf16x8 vb = *(const bf16x8*)&Vc[sidx(dh * 32 + lo, ks * 32 + hi * 16)];
        accO[dh] = __builtin_amdgcn_mfma_f32_32x32x16_bf16(pa[ks], vb, accO[dh], 0, 0, 0);
      }
    __builtin_amdgcn_s_setprio(0);
    __syncthreads();
    cur ^= 1;
  }

  // partial row-sum (lanes l, l^32 share q = l&31) and partial O -> f32 bufs
  l_run += __shfl_xor(l_run, 32);
  const long rrow = (long)pair * SQ_ + qb * 128 + w * 32;
  if (l < 32) Lp[(long)sp * (32 * SQ_) + rrow + lo] = l_run;
  float* Ow = Op + (long)sp * ((long)32 * SQ_ * HD_);
#pragma unroll
  for (int dh = 0; dh < 2; ++dh) {
#pragma unroll
    for (int r = 0; r < 16; ++r) {
      int qm = 4 * hi + (r & 3) + 8 * (r >> 2);
      Ow[(rrow + qm) * HD_ + dh * 32 + lo] = accO[dh][r];
    }
  }
}

// ---------------- combine split-K partials -> bf16 attnb --------------------
__global__ __launch_bounds__(256) void combine_o(
    const float* __restrict__ Op, const float* __restrict__ Lp,
    unsigned short* __restrict__ attnb) {
  const long SS = (long)32 * SQ_ * HD_;
  const int SL = 32 * SQ_;
  const long total = (long)SL * (HD_ / 4);
  for (long i = blockIdx.x * 256L + threadIdx.x; i < total;
       i += (long)gridDim.x * 256) {
    int row = (int)(i >> 4);
    int d0 = (int)(i & 15) * 4;
    float4 o0 = *(const float4*)&Op[(long)row * HD_ + d0];
    float4 o1 = *(const float4*)&Op[SS + (long)row * HD_ + d0];
    float rl = __builtin_amdgcn_rcpf(Lp[row] + Lp[SL + row]);
    int pair = row >> 11, q = row & 2047;
    int b = pair >> 4, h = pair & 15;
    unsigned short t[4] = {f2bf((o0.x + o1.x) * rl), f2bf((o0.y + o1.y) * rl),
                           f2bf((o0.z + o1.z) * rl), f2bf((o0.w + o1.w) * rl)};
    *(unsigned long long*)&attnb[(long)(b * SQ_ + q) * H_ + h * HD_ + d0] =
        *(unsigned long long*)t;
  }
}

extern "C" void kernel_launch(void* const* d_in, const int* in_sizes, int n_in,
                              void* d_out, int out_size, void* d_ws, size_t ws_size,
                              hipStream_t stream) {
  (void)in_sizes; (void)n_in; (void)out_size; (void)ws_size;
  const float* attender = (const float*)d_in[0];
  const float* attendee = (const float*)d_in[1];
  const int*   mask     = (const int*)d_in[2];
  const float* c_attn_w = (const float*)d_in[3];
  const float* c_attn_b = (const float*)d_in[4];
  const float* c_proj_w = (const float*)d_in[5];
  const float* c_proj_b = (const float*)d_in[6];
  const float* mlp_w    = (const float*)d_in[7];
  const float* mlp_b    = (const float*)d_in[8];
  float* out = (float*)d_out;

  char* ws = (char*)d_ws;
  size_t off = 0;
  auto alloc = [&](size_t bytes) {
    void* p = ws + off;
    off += (bytes + 255) & ~(size_t)255;
    return p;
  };
  unsigned short* cat   = (unsigned short*)alloc((size_t)4096 * 2048 * 2); // [attender_bf | attn]
  unsigned short* aet   = (unsigned short*)alloc((size_t)4096 * 1024 * 2);
  unsigned short* w_atT = (unsigned short*)alloc((size_t)3072 * 1024 * 2); // (3H, H)
  unsigned short* w_prT = (unsigned short*)alloc((size_t)1024 * 1024 * 2);
  unsigned short* w_mlT = (unsigned short*)alloc((size_t)1024 * 2048 * 2); // (H, 2H)
  unsigned short* Qb    = (unsigned short*)alloc((size_t)4096 * 1024 * 2);
  unsigned short* Kbuf  = (unsigned short*)alloc((size_t)4096 * 1024 * 2);
  unsigned short* Vtg   = (unsigned short*)alloc((size_t)B_ * NH_ * HD_ * SK_ * 2);
  unsigned short* attnb = (unsigned short*)alloc((size_t)4096 * 1024 * 2);
  float* Opart = (float*)alloc((size_t)2 * 32 * SQ_ * HD_ * 4);  // 32 MB
  float* Lpart = (float*)alloc((size_t)2 * 32 * SQ_ * 4);        // 512 KB

  const float LOG2E = 1.4426950408889634f;

  // all input converts: 2 launches
  conv_act<<<2048, 256, 0, stream>>>(attender, attendee, cat, aet);
  convT3<<<1536, 256, 0, stream>>>(c_attn_w, c_proj_w, mlp_w, w_atT, w_prT, w_mlT);

  // Q = (attender @ W[:, :H] + b) * log2(e)
  gemm_bt<2, 0><<<dim3(16, 32), 256, 0, stream>>>(
      cat, 2048, w_atT, 1024, c_attn_b, nullptr, LOG2E, Qb, nullptr, 1024, 1024);
  // K,V: K masked+normal, V transposed
  gemm_bt<4, 2><<<dim3(16, 32), 256, 0, stream>>>(
      aet, 1024, w_atT + (size_t)1024 * 1024, 1024, c_attn_b + 1024, mask, 1.f,
      Kbuf, Vtg, 1024, 1024);
  // attention: split-K partials, then combine -> attnb
  flash_attn<<<1024, 256, 0, stream>>>(Qb, Kbuf, Vtg, Opart, Lpart);
  combine_o<<<2048, 256, 0, stream>>>(Opart, Lpart, attnb);
  // proj -> cat[:, 1024:2048]
  gemm_bt<2, 0><<<dim3(16, 32), 256, 0, stream>>>(
      attnb, 1024, w_prT, 1024, c_proj_b, nullptr, 1.f, cat + 1024, nullptr, 2048, 1024);
  // out = gelu(cat @ mlp_w + mlp_b), f32
  gemm_bt<2, 1><<<dim3(16, 32), 256, 0, stream>>>(
      cat, 2048, w_mlT, 2048, mlp_b, nullptr, 1.f, out, nullptr, 1024, 2048);
}

// Round 13
// 174.864 us; speedup vs baseline: 1.0644x; 1.0644x over previous
//
#include <hip/hip_runtime.h>
#include <hip/hip_bf16.h>
#include <math.h>

#define H_ 1024
#define NH_ 16
#define HD_ 64
#define B_ 2
#define SQ_ 2048
#define SK_ 2048

using bf16x8 = __attribute__((ext_vector_type(8))) short;
using f32x4  = __attribute__((ext_vector_type(4))) float;
using f32x16 = __attribute__((ext_vector_type(16))) float;

static __device__ __forceinline__ unsigned short f2bf(float f) {
  union { float f; unsigned u; } v; v.f = f;
  unsigned r = v.u + 0x7fffu + ((v.u >> 16) & 1u);
  return (unsigned short)(r >> 16);
}

// two f32 -> packed bf16x2 dword via HW cvt (lo = a, hi = b)
static __device__ __forceinline__ unsigned cvtpk(float a, float b) {
  unsigned r;
  asm("v_cvt_pk_bf16_f32 %0, %1, %2" : "=v"(r) : "v"(a), "v"(b));
  return r;
}

static __device__ __forceinline__ void gl2lds16(const void* g, void* l) {
  __builtin_amdgcn_global_load_lds(
      (const __attribute__((address_space(1))) unsigned int*)g,
      (__attribute__((address_space(3))) unsigned int*)l, 16, 0, 0);
}

// swizzled index (shorts) within a [rows][64-short] tile, 128B rows
static __device__ __forceinline__ int sidx(int row, int cbyte) {
  return row * 64 + (((cbyte) ^ ((row & 7) << 4)) >> 1);
}

// ------------- merged activation convert: attender->cat, attendee->aet ------
__global__ __launch_bounds__(256) void conv_act(
    const float* __restrict__ att, const float* __restrict__ ate,
    unsigned short* __restrict__ cat, unsigned short* __restrict__ aet) {
  const long NV = (long)4096 * 1024 / 8;  // vec8 chunks per tensor
  for (long i = blockIdx.x * 256L + threadIdx.x; i < 2 * NV;
       i += (long)gridDim.x * 256) {
    const float* s;
    unsigned short* d;
    if (i < NV) {
      long e = i * 8;
      int r = (int)(e >> 10), c = (int)(e & 1023);
      s = att + e;
      d = cat + (long)r * 2048 + c;
    } else {
      long e = (i - NV) * 8;
      s = ate + e;
      d = aet + e;
    }
    unsigned short tmp[8];
#pragma unroll
    for (int j = 0; j < 8; ++j) tmp[j] = f2bf(s[j]);
    *(uint4*)d = *(uint4*)tmp;
  }
}

// ------------- merged weight transpose-convert (3 segments) -----------------
// f32 (R,C) -> bf16 (C,R). grid 1536: [0,768) attn_w, [768,1024) proj, rest mlp
__global__ __launch_bounds__(256) void convT3(
    const float* __restrict__ w_at, const float* __restrict__ w_pr,
    const float* __restrict__ w_ml, unsigned short* __restrict__ o_at,
    unsigned short* __restrict__ o_pr, unsigned short* __restrict__ o_ml) {
  __shared__ __align__(16) unsigned short Ls[64][68];
  int bx = blockIdx.x;
  const float* in;
  unsigned short* out;
  int R, C;
  if (bx < 768) {
    in = w_at; out = o_at; R = 1024; C = 3072;
  } else if (bx < 1024) {
    in = w_pr; out = o_pr; R = 1024; C = 1024; bx -= 768;
  } else {
    in = w_ml; out = o_ml; R = 2048; C = 1024; bx -= 1024;
  }
  int nct = C >> 6;
  int tr = bx / nct, tc = bx % nct;
  int r0 = tr * 64, c0 = tc * 64;
  int rr = threadIdx.x >> 4;
  int cc = (threadIdx.x & 15) * 4;
#pragma unroll
  for (int i = 0; i < 4; ++i) {
    int r = rr + 16 * i;
    float4 v = *(const float4*)&in[(long)(r0 + r) * C + c0 + cc];
    unsigned short t[4] = {f2bf(v.x), f2bf(v.y), f2bf(v.z), f2bf(v.w)};
    *(unsigned long long*)&Ls[r][cc] = *(unsigned long long*)t;
  }
  __syncthreads();
  int oc = threadIdx.x >> 2;
  int orr = (threadIdx.x & 3) * 16;
  unsigned short t[16];
#pragma unroll
  for (int j = 0; j < 16; ++j) t[j] = Ls[orr + j][oc];
  *(uint4*)&out[(long)(c0 + oc) * R + r0 + orr] = *(uint4*)&t[0];
  *(uint4*)&out[(long)(c0 + oc) * R + r0 + orr + 8] = *(uint4*)&t[8];
}

// ---------------- bf16 GEMM, B^T input, BK=64, double-buffered, swizzled ----
// Out = A(MxK) @ W(KxN) + bias, Bw = W^T (N rows, K cols). BN = NF*32.
// MODE 0: bf16 out0 (scaled by oscale). MODE 1: f32 out0 + GELU.
// MODE 2: split KV (col<H -> bf16 K*mask to out0; col>=H -> V^T to out1).
template <int NF, int MODE>
__global__ __launch_bounds__(256) void gemm_bt(
    const unsigned short* __restrict__ A, int lda,
    const unsigned short* __restrict__ Bw, int ldb,
    const float* __restrict__ bias, const int* __restrict__ msk, float oscale,
    void* __restrict__ out0, void* __restrict__ out1, int ldo, int K) {
  __shared__ __align__(16) unsigned short Al[2][128 * 64];
  __shared__ __align__(16) unsigned short Bl[2][NF * 32 * 64];
  const int tid = threadIdx.x;
  const int l = tid & 63, w = tid >> 6;
  const int wr = w >> 1, wc = w & 1;
  const int lq = l & 15, lh = l >> 4;
  const int m0 = blockIdx.y * 128, n0 = blockIdx.x * (NF * 32);

  const int swcol = (((tid & 7) ^ ((tid >> 3) & 7)) << 3);  // shorts
  const int rbase = w * 8 + (l >> 3);
  const unsigned short* gA = A + (long)(m0 + rbase) * lda + swcol;
  const unsigned short* gB = Bw + (long)(n0 + rbase) * ldb + swcol;

  f32x4 acc[4][NF];
#pragma unroll
  for (int a = 0; a < 4; ++a)
#pragma unroll
    for (int b = 0; b < NF; ++b) acc[a][b] = (f32x4){0.f, 0.f, 0.f, 0.f};

  auto stage = [&](int k0, int buf) {
#pragma unroll
    for (int i = 0; i < 4; ++i)
      gl2lds16(gA + (long)(i * 32) * lda + k0, &Al[buf][i * 2048 + w * 512]);
#pragma unroll
    for (int i = 0; i < NF; ++i)
      gl2lds16(gB + (long)(i * 32) * ldb + k0, &Bl[buf][i * 2048 + w * 512]);
  };

  const int NT = K >> 6;
  stage(0, 0);
  __syncthreads();
  int cur = 0;
  for (int t = 0; t < NT; ++t) {
    if (t + 1 < NT) stage((t + 1) << 6, cur ^ 1);
    bf16x8 af[4][2], bfr[NF][2];
#pragma unroll
    for (int a = 0; a < 4; ++a) {
      int row = wr * 64 + a * 16 + lq;
#pragma unroll
      for (int kk = 0; kk < 2; ++kk)
        af[a][kk] = *(const bf16x8*)&Al[cur][sidx(row, kk * 64 + lh * 16)];
    }
#pragma unroll
    for (int b = 0; b < NF; ++b) {
      int row = wc * (NF * 16) + b * 16 + lq;
#pragma unroll
      for (int kk = 0; kk < 2; ++kk)
        bfr[b][kk] = *(const bf16x8*)&Bl[cur][sidx(row, kk * 64 + lh * 16)];
    }
#pragma unroll
    for (int kk = 0; kk < 2; ++kk)
#pragma unroll
      for (int a = 0; a < 4; ++a)
#pragma unroll
        for (int b = 0; b < NF; ++b)
          acc[a][b] = __builtin_amdgcn_mfma_f32_16x16x32_bf16(
              af[a][kk], bfr[b][kk], acc[a][b], 0, 0, 0);
    __syncthreads();
    cur ^= 1;
  }

#pragma unroll
  for (int a = 0; a < 4; ++a) {
#pragma unroll
    for (int bb = 0; bb < NF; ++bb) {
      int col = n0 + wc * (NF * 16) + bb * 16 + lq;
      float bv = bias[col];
      int row0 = m0 + wr * 64 + a * 16 + lh * 4;
      if (MODE == 0) {
        unsigned short* O = (unsigned short*)out0;
#pragma unroll
        for (int r = 0; r < 4; ++r)
          O[(long)(row0 + r) * ldo + col] = f2bf((acc[a][bb][r] + bv) * oscale);
      } else if (MODE == 1) {
        float* O = (float*)out0;
#pragma unroll
        for (int r = 0; r < 4; ++r) {
          float v = acc[a][bb][r] + bv;
          float y = 0.7978845608028654f * (v + 0.044715f * v * v * v);
          O[(long)(row0 + r) * ldo + col] =
              v * __builtin_amdgcn_rcpf(1.f + __expf(-2.f * y));
        }
      } else {
        if (col < H_) {
          unsigned short* O = (unsigned short*)out0;
#pragma unroll
          for (int r = 0; r < 4; ++r) {
            float mk = (float)msk[row0 + r];
            O[(long)(row0 + r) * ldo + col] = f2bf((acc[a][bb][r] + bv) * mk);
          }
        } else {
          int vcol = col - H_, hh = vcol >> 6, dd = vcol & 63;
          int bi = row0 >> 11, k = row0 & 2047;
          unsigned short t[4];
#pragma unroll
          for (int r = 0; r < 4; ++r) t[r] = f2bf(acc[a][bb][r] + bv);
          *(unsigned long long*)((unsigned short*)out1 +
                                 (((long)(bi * NH_ + hh) * HD_ + dd) << 11) + k) =
              *(unsigned long long*)t;
        }
      }
    }
  }
}

// ---------------- flash attention: 32x32 MFMA, in-register P (T12) ----------
// grid 512 (XCD-remapped), block = 4 waves x 32 q. KV tiles of 64.
// Q pre-scaled by log2(e); K pre-masked; V pre-transposed (B,NH,HD,SK).
// Swapped QK^T: lane owns q = lane&31; P assembled in regs via
// cvt_pk + permlane32_swap; P never touches LDS. (r10 best + zreg peel)
__global__ __launch_bounds__(256) void flash_attn(
    const unsigned short* __restrict__ Qb,
    const unsigned short* __restrict__ Kb,
    const unsigned short* __restrict__ Vtg,
    unsigned short* __restrict__ Ob) {
  __shared__ __align__(16) unsigned short Kl[2][64 * 64];
  __shared__ __align__(16) unsigned short Vl[2][64 * 64];
  __shared__ __align__(16) float Lr[4][32];
  const int tid = threadIdx.x;
  const int l = tid & 63, w = tid >> 6;
  const int lo = l & 31, hi = l >> 5;
  const int id = blockIdx.x;
  const int xcd = id & 7, sub = id >> 3;
  const int pair = xcd * 4 + (sub >> 4);  // (b*NH+h): 4 pairs per XCD
  const int qb = sub & 15;
  const int b = pair >> 4, h = pair & 15;
  const int brow = b * SQ_ + qb * 128 + w * 32;

  // Q B-fragments (32x32x16: lane holds Q[q=lo][d = dstep*16 + hi*8 + j])
  bf16x8 qf[4];
  {
    const unsigned short* qp = Qb + (long)(brow + lo) * H_ + h * HD_ + hi * 8;
#pragma unroll
    for (int d = 0; d < 4; ++d) qf[d] = *(const bf16x8*)(qp + d * 16);
  }

  // staging: lane covers rows j*32 + w*8 + (l>>3), bytecol (l&7)*16 (j=0,1);
  // source col pre-swizzled so linear LDS dest lands XOR-swizzled (rule #21)
  const int srow = w * 8 + (l >> 3);
  const int swc = ((l & 7) ^ ((l >> 3) & 7)) << 3;  // shorts
  const unsigned short* Kg = Kb + ((long)b * SK_ + srow) * H_ + h * HD_ + swc;
  const unsigned short* Vg = Vtg + ((long)(b * NH_ + h) * HD_ + srow) * SK_ + swc;

  auto stage = [&](int kt, int buf) {
    const unsigned short* ks = Kg + (long)kt * 64 * H_;
    const unsigned short* vs = Vg + kt * 64;
    char* kd = (char*)&Kl[buf][0] + w * 1024;
    char* vd = (char*)&Vl[buf][0] + w * 1024;
    gl2lds16(ks, kd);
    gl2lds16(ks + (long)32 * H_, kd + 4096);
    gl2lds16(vs, vd);
    gl2lds16(vs + (long)32 * SK_, vd + 4096);
  };

  f32x16 zreg, accO[2];
#pragma unroll
  for (int r = 0; r < 16; ++r) zreg[r] = 0.f;
#pragma unroll
  for (int i = 0; i < 2; ++i)
#pragma unroll
    for (int r = 0; r < 16; ++r) accO[i][r] = 0.f;
  float l_run = 0.f;

  stage(0, 0);
  __syncthreads();
  int cur = 0;
  const int NT = SK_ / 64;
  for (int kt = 0; kt < NT; ++kt) {
    if (kt + 1 < NT) stage(kt + 1, cur ^ 1);
    const unsigned short* Kc = &Kl[cur][0];
    const unsigned short* Vc = &Vl[cur][0];

    // S^T[k][q] = K_tile(64x64) @ Q^T(64x32): two 32x32 halves over k.
    // ds=0 peeled with C = persistent zero reg (no per-tile acc zero-init).
    __builtin_amdgcn_s_setprio(1);
    bf16x8 ka0 = *(const bf16x8*)&Kc[sidx(lo, hi * 16)];
    bf16x8 ka1 = *(const bf16x8*)&Kc[sidx(32 + lo, hi * 16)];
    f32x16 s0 = __builtin_amdgcn_mfma_f32_32x32x16_bf16(ka0, qf[0], zreg, 0, 0, 0);
    f32x16 s1 = __builtin_amdgcn_mfma_f32_32x32x16_bf16(ka1, qf[0], zreg, 0, 0, 0);
#pragma unroll
    for (int ds = 1; ds < 4; ++ds) {
      ka0 = *(const bf16x8*)&Kc[sidx(lo, ds * 32 + hi * 16)];
      ka1 = *(const bf16x8*)&Kc[sidx(32 + lo, ds * 32 + hi * 16)];
      s0 = __builtin_amdgcn_mfma_f32_32x32x16_bf16(ka0, qf[ds], s0, 0, 0, 0);
      s1 = __builtin_amdgcn_mfma_f32_32x32x16_bf16(ka1, qf[ds], s1, 0, 0, 0);
    }
    __builtin_amdgcn_s_setprio(0);

    // P = 2^s (Q carries log2e; shift-free, cancels in normalization).
    // Lane holds, for q=lo, k = kh*32 + 4*hi + {(r&3)+8*(r>>2)}.
    // Assemble PV A-frags (k = kstep*16 + hi*8 + j) via cvt_pk + permlane32.
    bf16x8 pa[4];
    float ps = 0.f;
#pragma unroll
    for (int kh = 0; kh < 2; ++kh) {
      const f32x16& s = kh ? s1 : s0;
      float p[16];
#pragma unroll
      for (int r = 0; r < 16; ++r) { p[r] = exp2f(s[r]); ps += p[r]; }
#pragma unroll
      for (int g = 0; g < 2; ++g) {
        unsigned X0 = cvtpk(p[g * 8 + 0], p[g * 8 + 1]);
        unsigned X1 = cvtpk(p[g * 8 + 2], p[g * 8 + 3]);
        unsigned Y0 = cvtpk(p[g * 8 + 4], p[g * 8 + 5]);
        unsigned Y1 = cvtpk(p[g * 8 + 6], p[g * 8 + 7]);
        asm("v_permlane32_swap_b32 %0, %1" : "+v"(X0), "+v"(Y0));
        asm("v_permlane32_swap_b32 %0, %1" : "+v"(X1), "+v"(Y1));
        union { unsigned u[4]; bf16x8 v; } cc;
        cc.u[0] = X0; cc.u[1] = X1; cc.u[2] = Y0; cc.u[3] = Y1;
        pa[kh * 2 + g] = cc.v;
      }
    }
    l_run += ps;

    // O[q][d] += P(32x64) @ V(64x64): two 32x32 outputs over d
    __builtin_amdgcn_s_setprio(1);
#pragma unroll
    for (int dh = 0; dh < 2; ++dh)
#pragma unroll
      for (int ks = 0; ks < 4; ++ks) {
        bf16x8 vb = *(const bf16x8*)&Vc[sidx(dh * 32 + lo, ks * 32 + hi * 16)];
        accO[dh] = __builtin_amdgcn_mfma_f32_32x32x16_bf16(pa[ks], vb, accO[dh], 0, 0, 0);
      }
    __builtin_amdgcn_s_setprio(0);
    __syncthreads();
    cur ^= 1;
  }

  // row-sum: own half + partner half (lanes l, l^32 share q = l&31)
  l_run += __shfl_xor(l_run, 32);
  if (l < 32) Lr[w][lo] = __builtin_amdgcn_rcpf(l_run);
  // redistribute 1/l to the C-layout (q = 4*hi + (r&3) + 8*(r>>2))
  f32x4 rsq[4];
#pragma unroll
  for (int rq = 0; rq < 4; ++rq)
    rsq[rq] = *(const f32x4*)&Lr[w][4 * hi + 8 * rq];

#pragma unroll
  for (int dh = 0; dh < 2; ++dh) {
#pragma unroll
    for (int r = 0; r < 16; ++r) {
      int qm = 4 * hi + (r & 3) + 8 * (r >> 2);
      float v = accO[dh][r] * rsq[r >> 2][r & 3];
      Ob[(long)(brow + qm) * H_ + h * HD_ + dh * 32 + lo] = f2bf(v);
    }
  }
}

extern "C" void kernel_launch(void* const* d_in, const int* in_sizes, int n_in,
                              void* d_out, int out_size, void* d_ws, size_t ws_size,
                              hipStream_t stream) {
  (void)in_sizes; (void)n_in; (void)out_size; (void)ws_size;
  const float* attender = (const float*)d_in[0];
  const float* attendee = (const float*)d_in[1];
  const int*   mask     = (const int*)d_in[2];
  const float* c_attn_w = (const float*)d_in[3];
  const float* c_attn_b = (const float*)d_in[4];
  const float* c_proj_w = (const float*)d_in[5];
  const float* c_proj_b = (const float*)d_in[6];
  const float* mlp_w    = (const float*)d_in[7];
  const float* mlp_b    = (const float*)d_in[8];
  float* out = (float*)d_out;

  char* ws = (char*)d_ws;
  size_t off = 0;
  auto alloc = [&](size_t bytes) {
    void* p = ws + off;
    off += (bytes + 255) & ~(size_t)255;
    return p;
  };
  unsigned short* cat   = (unsigned short*)alloc((size_t)4096 * 2048 * 2); // [attender_bf | attn]
  unsigned short* aet   = (unsigned short*)alloc((size_t)4096 * 1024 * 2);
  unsigned short* w_atT = (unsigned short*)alloc((size_t)3072 * 1024 * 2); // (3H, H)
  unsigned short* w_prT = (unsigned short*)alloc((size_t)1024 * 1024 * 2);
  unsigned short* w_mlT = (unsigned short*)alloc((size_t)1024 * 2048 * 2); // (H, 2H)
  unsigned short* Qb    = (unsigned short*)alloc((size_t)4096 * 1024 * 2);
  unsigned short* Kbuf  = (unsigned short*)alloc((size_t)4096 * 1024 * 2);
  unsigned short* Vtg   = (unsigned short*)alloc((size_t)B_ * NH_ * HD_ * SK_ * 2);
  unsigned short* attnb = (unsigned short*)alloc((size_t)4096 * 1024 * 2);

  const float LOG2E = 1.4426950408889634f;

  // all input converts: 2 launches
  conv_act<<<2048, 256, 0, stream>>>(attender, attendee, cat, aet);
  convT3<<<1536, 256, 0, stream>>>(c_attn_w, c_proj_w, mlp_w, w_atT, w_prT, w_mlT);

  // Q = (attender @ W[:, :H] + b) * log2(e)
  gemm_bt<2, 0><<<dim3(16, 32), 256, 0, stream>>>(
      cat, 2048, w_atT, 1024, c_attn_b, nullptr, LOG2E, Qb, nullptr, 1024, 1024);
  // K,V: K masked+normal, V transposed
  gemm_bt<4, 2><<<dim3(16, 32), 256, 0, stream>>>(
      aet, 1024, w_atT + (size_t)1024 * 1024, 1024, c_attn_b + 1024, mask, 1.f,
      Kbuf, Vtg, 1024, 1024);
  // attention -> attnb
  flash_attn<<<512, 256, 0, stream>>>(Qb, Kbuf, Vtg, attnb);
  // proj -> cat[:, 1024:2048]
  gemm_bt<2, 0><<<dim3(16, 32), 256, 0, stream>>>(
      attnb, 1024, w_prT, 1024, c_proj_b, nullptr, 1.f, cat + 1024, nullptr, 2048, 1024);
  // out = gelu(cat @ mlp_w + mlp_b), f32
  gemm_bt<2, 1><<<dim3(16, 32), 256, 0, stream>>>(
      cat, 2048, w_mlT, 2048, mlp_b, nullptr, 1.f, out, nullptr, 1024, 2048);
}

// Round 14
// 171.128 us; speedup vs baseline: 1.0876x; 1.0218x over previous
//
#include <hip/hip_runtime.h>
#include <hip/hip_bf16.h>
#include <math.h>

#define H_ 1024
#define NH_ 16
#define HD_ 64
#define B_ 2
#define SQ_ 2048
#define SK_ 2048

using bf16x8 = __attribute__((ext_vector_type(8))) short;
using f32x4  = __attribute__((ext_vector_type(4))) float;
using f32x16 = __attribute__((ext_vector_type(16))) float;

static __device__ __forceinline__ unsigned short f2bf(float f) {
  union { float f; unsigned u; } v; v.f = f;
  unsigned r = v.u + 0x7fffu + ((v.u >> 16) & 1u);
  return (unsigned short)(r >> 16);
}

// two f32 -> packed bf16x2 dword via HW cvt (lo = a, hi = b)
static __device__ __forceinline__ unsigned cvtpk(float a, float b) {
  unsigned r;
  asm("v_cvt_pk_bf16_f32 %0, %1, %2" : "=v"(r) : "v"(a), "v"(b));
  return r;
}

static __device__ __forceinline__ void gl2lds16(const void* g, void* l) {
  __builtin_amdgcn_global_load_lds(
      (const __attribute__((address_space(1))) unsigned int*)g,
      (__attribute__((address_space(3))) unsigned int*)l, 16, 0, 0);
}

// swizzled index (shorts) within a [rows][64-short] tile, 128B rows
static __device__ __forceinline__ int sidx(int row, int cbyte) {
  return row * 64 + (((cbyte) ^ ((row & 7) << 4)) >> 1);
}

// ------------- merged input convert: weights (transposed) + activations -----
// grid 3584: [0,768) attn_w^T, [768,1024) proj^T, [1024,1536) mlp^T,
// [1536,3584) activation f32->bf16 grid-stride (attender->cat, attendee->aet)
__global__ __launch_bounds__(256) void conv_all(
    const float* __restrict__ att, const float* __restrict__ ate,
    const float* __restrict__ w_at, const float* __restrict__ w_pr,
    const float* __restrict__ w_ml,
    unsigned short* __restrict__ cat, unsigned short* __restrict__ aet,
    unsigned short* __restrict__ o_at, unsigned short* __restrict__ o_pr,
    unsigned short* __restrict__ o_ml) {
  __shared__ __align__(16) unsigned short Ls[64][68];
  int bx = blockIdx.x;
  if (bx >= 1536) {
    const long NV = (long)4096 * 1024 / 8;  // vec8 chunks per tensor
    for (long i = (bx - 1536) * 256L + threadIdx.x; i < 2 * NV;
         i += 2048L * 256) {
      const float* s;
      unsigned short* d;
      if (i < NV) {
        long e = i * 8;
        int r = (int)(e >> 10), c = (int)(e & 1023);
        s = att + e;
        d = cat + (long)r * 2048 + c;
      } else {
        long e = (i - NV) * 8;
        s = ate + e;
        d = aet + e;
      }
      unsigned short tmp[8];
#pragma unroll
      for (int j = 0; j < 8; ++j) tmp[j] = f2bf(s[j]);
      *(uint4*)d = *(uint4*)tmp;
    }
    return;
  }
  const float* in;
  unsigned short* out;
  int R, C;
  if (bx < 768) {
    in = w_at; out = o_at; R = 1024; C = 3072;
  } else if (bx < 1024) {
    in = w_pr; out = o_pr; R = 1024; C = 1024; bx -= 768;
  } else {
    in = w_ml; out = o_ml; R = 2048; C = 1024; bx -= 1024;
  }
  int nct = C >> 6;
  int tr = bx / nct, tc = bx % nct;
  int r0 = tr * 64, c0 = tc * 64;
  int rr = threadIdx.x >> 4;
  int cc = (threadIdx.x & 15) * 4;
#pragma unroll
  for (int i = 0; i < 4; ++i) {
    int r = rr + 16 * i;
    float4 v = *(const float4*)&in[(long)(r0 + r) * C + c0 + cc];
    unsigned short t[4] = {f2bf(v.x), f2bf(v.y), f2bf(v.z), f2bf(v.w)};
    *(unsigned long long*)&Ls[r][cc] = *(unsigned long long*)t;
  }
  __syncthreads();
  int oc = threadIdx.x >> 2;
  int orr = (threadIdx.x & 3) * 16;
  unsigned short t[16];
#pragma unroll
  for (int j = 0; j < 16; ++j) t[j] = Ls[orr + j][oc];
  *(uint4*)&out[(long)(c0 + oc) * R + r0 + orr] = *(uint4*)&t[0];
  *(uint4*)&out[(long)(c0 + oc) * R + r0 + orr + 8] = *(uint4*)&t[8];
}

// ---------------- bf16 GEMM, B^T input, BK=64, double-buffered, swizzled ----
// Out = A(MxK) @ W(KxN) + bias, Bw = W^T (N rows, K cols). BN = NF*32.
// MODE 0: bf16 out0 (scaled by oscale). MODE 1: f32 out0 + GELU.
// MODE 2: split KV (col<H -> bf16 K*mask to out0; col>=H -> V^T to out1).
template <int NF, int MODE>
__global__ __launch_bounds__(256) void gemm_bt(
    const unsigned short* __restrict__ A, int lda,
    const unsigned short* __restrict__ Bw, int ldb,
    const float* __restrict__ bias, const int* __restrict__ msk, float oscale,
    void* __restrict__ out0, void* __restrict__ out1, int ldo, int K) {
  __shared__ __align__(16) unsigned short Al[2][128 * 64];
  __shared__ __align__(16) unsigned short Bl[2][NF * 32 * 64];
  const int tid = threadIdx.x;
  const int l = tid & 63, w = tid >> 6;
  const int wr = w >> 1, wc = w & 1;
  const int lq = l & 15, lh = l >> 4;
  const int m0 = blockIdx.y * 128, n0 = blockIdx.x * (NF * 32);

  const int swcol = (((tid & 7) ^ ((tid >> 3) & 7)) << 3);  // shorts
  const int rbase = w * 8 + (l >> 3);
  const unsigned short* gA = A + (long)(m0 + rbase) * lda + swcol;
  const unsigned short* gB = Bw + (long)(n0 + rbase) * ldb + swcol;

  f32x4 acc[4][NF];
#pragma unroll
  for (int a = 0; a < 4; ++a)
#pragma unroll
    for (int b = 0; b < NF; ++b) acc[a][b] = (f32x4){0.f, 0.f, 0.f, 0.f};

  auto stage = [&](int k0, int buf) {
#pragma unroll
    for (int i = 0; i < 4; ++i)
      gl2lds16(gA + (long)(i * 32) * lda + k0, &Al[buf][i * 2048 + w * 512]);
#pragma unroll
    for (int i = 0; i < NF; ++i)
      gl2lds16(gB + (long)(i * 32) * ldb + k0, &Bl[buf][i * 2048 + w * 512]);
  };

  const int NT = K >> 6;
  stage(0, 0);
  __syncthreads();
  int cur = 0;
  for (int t = 0; t < NT; ++t) {
    if (t + 1 < NT) stage((t + 1) << 6, cur ^ 1);
    bf16x8 af[4][2], bfr[NF][2];
#pragma unroll
    for (int a = 0; a < 4; ++a) {
      int row = wr * 64 + a * 16 + lq;
#pragma unroll
      for (int kk = 0; kk < 2; ++kk)
        af[a][kk] = *(const bf16x8*)&Al[cur][sidx(row, kk * 64 + lh * 16)];
    }
#pragma unroll
    for (int b = 0; b < NF; ++b) {
      int row = wc * (NF * 16) + b * 16 + lq;
#pragma unroll
      for (int kk = 0; kk < 2; ++kk)
        bfr[b][kk] = *(const bf16x8*)&Bl[cur][sidx(row, kk * 64 + lh * 16)];
    }
#pragma unroll
    for (int kk = 0; kk < 2; ++kk)
#pragma unroll
      for (int a = 0; a < 4; ++a)
#pragma unroll
        for (int b = 0; b < NF; ++b)
          acc[a][b] = __builtin_amdgcn_mfma_f32_16x16x32_bf16(
              af[a][kk], bfr[b][kk], acc[a][b], 0, 0, 0);
    __syncthreads();
    cur ^= 1;
  }

#pragma unroll
  for (int a = 0; a < 4; ++a) {
#pragma unroll
    for (int bb = 0; bb < NF; ++bb) {
      int col = n0 + wc * (NF * 16) + bb * 16 + lq;
      float bv = bias[col];
      int row0 = m0 + wr * 64 + a * 16 + lh * 4;
      if (MODE == 0) {
        unsigned short* O = (unsigned short*)out0;
#pragma unroll
        for (int r = 0; r < 4; ++r)
          O[(long)(row0 + r) * ldo + col] = f2bf((acc[a][bb][r] + bv) * oscale);
      } else if (MODE == 1) {
        float* O = (float*)out0;
#pragma unroll
        for (int r = 0; r < 4; ++r) {
          float v = acc[a][bb][r] + bv;
          float y = 0.7978845608028654f * (v + 0.044715f * v * v * v);
          O[(long)(row0 + r) * ldo + col] =
              v * __builtin_amdgcn_rcpf(1.f + __expf(-2.f * y));
        }
      } else {
        if (col < H_) {
          unsigned short* O = (unsigned short*)out0;
#pragma unroll
          for (int r = 0; r < 4; ++r) {
            float mk = (float)msk[row0 + r];
            O[(long)(row0 + r) * ldo + col] = f2bf((acc[a][bb][r] + bv) * mk);
          }
        } else {
          int vcol = col - H_, hh = vcol >> 6, dd = vcol & 63;
          int bi = row0 >> 11, k = row0 & 2047;
          unsigned short t[4];
#pragma unroll
          for (int r = 0; r < 4; ++r) t[r] = f2bf(acc[a][bb][r] + bv);
          *(unsigned long long*)((unsigned short*)out1 +
                                 (((long)(bi * NH_ + hh) * HD_ + dd) << 11) + k) =
              *(unsigned long long*)t;
        }
      }
    }
  }
}

// ---------------- flash attention: 32x32 MFMA, in-register P (T12) ----------
// grid 512 (XCD-remapped), block = 4 waves x 32 q. KV tiles of 64.
// Q pre-scaled by log2(e); K pre-masked; V pre-transposed (B,NH,HD,SK).
// Swapped QK^T: lane owns q = lane&31; P assembled in regs via
// cvt_pk + permlane32_swap; P never touches LDS. (= round-10 measured-best)
__global__ __launch_bounds__(256) void flash_attn(
    const unsigned short* __restrict__ Qb,
    const unsigned short* __restrict__ Kb,
    const unsigned short* __restrict__ Vtg,
    unsigned short* __restrict__ Ob) {
  __shared__ __align__(16) unsigned short Kl[2][64 * 64];
  __shared__ __align__(16) unsigned short Vl[2][64 * 64];
  __shared__ __align__(16) float Lr[4][32];
  const int tid = threadIdx.x;
  const int l = tid & 63, w = tid >> 6;
  const int lo = l & 31, hi = l >> 5;
  const int id = blockIdx.x;
  const int xcd = id & 7, sub = id >> 3;
  const int pair = xcd * 4 + (sub >> 4);  // (b*NH+h): 4 pairs per XCD
  const int qb = sub & 15;
  const int b = pair >> 4, h = pair & 15;
  const int brow = b * SQ_ + qb * 128 + w * 32;

  // Q B-fragments (32x32x16: lane holds Q[q=lo][d = dstep*16 + hi*8 + j])
  bf16x8 qf[4];
  {
    const unsigned short* qp = Qb + (long)(brow + lo) * H_ + h * HD_ + hi * 8;
#pragma unroll
    for (int d = 0; d < 4; ++d) qf[d] = *(const bf16x8*)(qp + d * 16);
  }

  // staging: lane covers rows j*32 + w*8 + (l>>3), bytecol (l&7)*16 (j=0,1);
  // source col pre-swizzled so linear LDS dest lands XOR-swizzled (rule #21)
  const int srow = w * 8 + (l >> 3);
  const int swc = ((l & 7) ^ ((l >> 3) & 7)) << 3;  // shorts
  const unsigned short* Kg = Kb + ((long)b * SK_ + srow) * H_ + h * HD_ + swc;
  const unsigned short* Vg = Vtg + ((long)(b * NH_ + h) * HD_ + srow) * SK_ + swc;

  auto stage = [&](int kt, int buf) {
    const unsigned short* ks = Kg + (long)kt * 64 * H_;
    const unsigned short* vs = Vg + kt * 64;
    char* kd = (char*)&Kl[buf][0] + w * 1024;
    char* vd = (char*)&Vl[buf][0] + w * 1024;
    gl2lds16(ks, kd);
    gl2lds16(ks + (long)32 * H_, kd + 4096);
    gl2lds16(vs, vd);
    gl2lds16(vs + (long)32 * SK_, vd + 4096);
  };

  f32x16 accO[2];
#pragma unroll
  for (int i = 0; i < 2; ++i)
#pragma unroll
    for (int r = 0; r < 16; ++r) accO[i][r] = 0.f;
  float l_run = 0.f;

  stage(0, 0);
  __syncthreads();
  int cur = 0;
  const int NT = SK_ / 64;
  for (int kt = 0; kt < NT; ++kt) {
    if (kt + 1 < NT) stage(kt + 1, cur ^ 1);
    const unsigned short* Kc = &Kl[cur][0];
    const unsigned short* Vc = &Vl[cur][0];

    // S^T[k][q] = K_tile(64x64) @ Q^T(64x32): two 32x32 halves over k
    f32x16 s0, s1;
#pragma unroll
    for (int r = 0; r < 16; ++r) { s0[r] = 0.f; s1[r] = 0.f; }
    __builtin_amdgcn_s_setprio(1);
#pragma unroll
    for (int ds = 0; ds < 4; ++ds) {
      bf16x8 ka0 = *(const bf16x8*)&Kc[sidx(lo, ds * 32 + hi * 16)];
      bf16x8 ka1 = *(const bf16x8*)&Kc[sidx(32 + lo, ds * 32 + hi * 16)];
      s0 = __builtin_amdgcn_mfma_f32_32x32x16_bf16(ka0, qf[ds], s0, 0, 0, 0);
      s1 = __builtin_amdgcn_mfma_f32_32x32x16_bf16(ka1, qf[ds], s1, 0, 0, 0);
    }
    __builtin_amdgcn_s_setprio(0);

    // P = 2^s (Q carries log2e; shift-free, cancels in normalization).
    // Lane holds, for q=lo, k = kh*32 + 4*hi + {(r&3)+8*(r>>2)}.
    // Assemble PV A-frags (k = kstep*16 + hi*8 + j) via cvt_pk + permlane32.
    bf16x8 pa[4];
    float ps = 0.f;
#pragma unroll
    for (int kh = 0; kh < 2; ++kh) {
      const f32x16& s = kh ? s1 : s0;
      float p[16];
#pragma unroll
      for (int r = 0; r < 16; ++r) { p[r] = exp2f(s[r]); ps += p[r]; }
#pragma unroll
      for (int g = 0; g < 2; ++g) {
        unsigned X0 = cvtpk(p[g * 8 + 0], p[g * 8 + 1]);
        unsigned X1 = cvtpk(p[g * 8 + 2], p[g * 8 + 3]);
        unsigned Y0 = cvtpk(p[g * 8 + 4], p[g * 8 + 5]);
        unsigned Y1 = cvtpk(p[g * 8 + 6], p[g * 8 + 7]);
        asm("v_permlane32_swap_b32 %0, %1" : "+v"(X0), "+v"(Y0));
        asm("v_permlane32_swap_b32 %0, %1" : "+v"(X1), "+v"(Y1));
        union { unsigned u[4]; bf16x8 v; } cc;
        cc.u[0] = X0; cc.u[1] = X1; cc.u[2] = Y0; cc.u[3] = Y1;
        pa[kh * 2 + g] = cc.v;
      }
    }
    l_run += ps;

    // O[q][d] += P(32x64) @ V(64x64): two 32x32 outputs over d
    __builtin_amdgcn_s_setprio(1);
#pragma unroll
    for (int dh = 0; dh < 2; ++dh)
#pragma unroll
      for (int ks = 0; ks < 4; ++ks) {
        bf16x8 vb = *(const bf16x8*)&Vc[sidx(dh * 32 + lo, ks * 32 + hi * 16)];
        accO[dh] = __builtin_amdgcn_mfma_f32_32x32x16_bf16(pa[ks], vb, accO[dh], 0, 0, 0);
      }
    __builtin_amdgcn_s_setprio(0);
    __syncthreads();
    cur ^= 1;
  }

  // row-sum: own half + partner half (lanes l, l^32 share q = l&31)
  l_run += __shfl_xor(l_run, 32);
  if (l < 32) Lr[w][lo] = __builtin_amdgcn_rcpf(l_run);
  // redistribute 1/l to the C-layout (q = 4*hi + (r&3) + 8*(r>>2))
  f32x4 rsq[4];
#pragma unroll
  for (int rq = 0; rq < 4; ++rq)
    rsq[rq] = *(const f32x4*)&Lr[w][4 * hi + 8 * rq];

#pragma unroll
  for (int dh = 0; dh < 2; ++dh) {
#pragma unroll
    for (int r = 0; r < 16; ++r) {
      int qm = 4 * hi + (r & 3) + 8 * (r >> 2);
      float v = accO[dh][r] * rsq[r >> 2][r & 3];
      Ob[(long)(brow + qm) * H_ + h * HD_ + dh * 32 + lo] = f2bf(v);
    }
  }
}

extern "C" void kernel_launch(void* const* d_in, const int* in_sizes, int n_in,
                              void* d_out, int out_size, void* d_ws, size_t ws_size,
                              hipStream_t stream) {
  (void)in_sizes; (void)n_in; (void)out_size; (void)ws_size;
  const float* attender = (const float*)d_in[0];
  const float* attendee = (const float*)d_in[1];
  const int*   mask     = (const int*)d_in[2];
  const float* c_attn_w = (const float*)d_in[3];
  const float* c_attn_b = (const float*)d_in[4];
  const float* c_proj_w = (const float*)d_in[5];
  const float* c_proj_b = (const float*)d_in[6];
  const float* mlp_w    = (const float*)d_in[7];
  const float* mlp_b    = (const float*)d_in[8];
  float* out = (float*)d_out;

  char* ws = (char*)d_ws;
  size_t off = 0;
  auto alloc = [&](size_t bytes) {
    void* p = ws + off;
    off += (bytes + 255) & ~(size_t)255;
    return p;
  };
  unsigned short* cat   = (unsigned short*)alloc((size_t)4096 * 2048 * 2); // [attender_bf | attn]
  unsigned short* aet   = (unsigned short*)alloc((size_t)4096 * 1024 * 2);
  unsigned short* w_atT = (unsigned short*)alloc((size_t)3072 * 1024 * 2); // (3H, H)
  unsigned short* w_prT = (unsigned short*)alloc((size_t)1024 * 1024 * 2);
  unsigned short* w_mlT = (unsigned short*)alloc((size_t)1024 * 2048 * 2); // (H, 2H)
  unsigned short* Qb    = (unsigned short*)alloc((size_t)4096 * 1024 * 2);
  unsigned short* Kbuf  = (unsigned short*)alloc((size_t)4096 * 1024 * 2);
  unsigned short* Vtg   = (unsigned short*)alloc((size_t)B_ * NH_ * HD_ * SK_ * 2);
  unsigned short* attnb = (unsigned short*)alloc((size_t)4096 * 1024 * 2);

  const float LOG2E = 1.4426950408889634f;

  // all input converts in one launch (weights transposed + activations)
  conv_all<<<3584, 256, 0, stream>>>(attender, attendee, c_attn_w, c_proj_w,
                                     mlp_w, cat, aet, w_atT, w_prT, w_mlT);

  // Q = (attender @ W[:, :H] + b) * log2(e)
  gemm_bt<2, 0><<<dim3(16, 32), 256, 0, stream>>>(
      cat, 2048, w_atT, 1024, c_attn_b, nullptr, LOG2E, Qb, nullptr, 1024, 1024);
  // K,V: K masked+normal, V transposed
  gemm_bt<4, 2><<<dim3(16, 32), 256, 0, stream>>>(
      aet, 1024, w_atT + (size_t)1024 * 1024, 1024, c_attn_b + 1024, mask, 1.f,
      Kbuf, Vtg, 1024, 1024);
  // attention -> attnb
  flash_attn<<<512, 256, 0, stream>>>(Qb, Kbuf, Vtg, attnb);
  // proj -> cat[:, 1024:2048]
  gemm_bt<2, 0><<<dim3(16, 32), 256, 0, stream>>>(
      attnb, 1024, w_prT, 1024, c_proj_b, nullptr, 1.f, cat + 1024, nullptr, 2048, 1024);
  // out = gelu(cat @ mlp_w + mlp_b), f32
  gemm_bt<2, 1><<<dim3(16, 32), 256, 0, stream>>>(
      cat, 2048, w_mlT, 2048, mlp_b, nullptr, 1.f, out, nullptr, 1024, 2048);
}